// Round 1
// baseline (209.004 us; speedup 1.0000x reference)
//
#include <hip/hip_runtime.h>
#include <hip/hip_bf16.h>
#include <stdint.h>

#define B_ROWS 16384   // batch rows (M)
#define C_ROWS 2048    // class rows (N)
#define D_FULL 512     // input feature dim
#define KP     512     // padded K (511 real + 1 zero col)

#define BM 128
#define BN 128
#define BK 64

typedef __attribute__((ext_vector_type(8))) short bf16x8;
typedef __attribute__((ext_vector_type(4))) float f32x4;

typedef __attribute__((address_space(1))) void glb_void;
typedef __attribute__((address_space(3))) void lds_void;

// async global->LDS, 16B per lane; LDS dest = wave-uniform base + lane*16
__device__ __forceinline__ void gld16(const void* g, void* l) {
    __builtin_amdgcn_global_load_lds((glb_void*)(uintptr_t)g,
                                     (lds_void*)(uintptr_t)l, 16, 0, 0);
}

// ---------------------------------------------------------------------------
// Prep: per row, cast cols [1..511] -> bf16 (padded to 512 with trailing 0),
// and compute norm = sqrt(1 + sum(rest^2)) in fp32.
// One 256-thread block per row; rows [0,16384) = x, [16384,18432) = points.
// ---------------------------------------------------------------------------
__global__ __launch_bounds__(256) void prep_kernel(
    const float* __restrict__ x, const float* __restrict__ pts,
    unsigned short* __restrict__ Abf, unsigned short* __restrict__ Bbf,
    float* __restrict__ xn, float* __restrict__ pn)
{
    int row = blockIdx.x;
    const float* src;
    unsigned short* dst;
    float* nrm;
    if (row < B_ROWS) {
        src = x + (size_t)row * D_FULL;
        dst = Abf + (size_t)row * KP;
        nrm = xn + row;
    } else {
        int r = row - B_ROWS;
        src = pts + (size_t)r * D_FULL;
        dst = Bbf + (size_t)r * KP;
        nrm = pn + r;
    }
    int t = threadIdx.x;
    float v0 = src[t + 1];                        // k = t        (t in [0,255])
    float v1 = (t < 255) ? src[t + 257] : 0.0f;   // k = t + 256  (k==511 -> pad 0)
    __hip_bfloat16 b0 = __float2bfloat16(v0);
    __hip_bfloat16 b1 = __float2bfloat16(v1);
    dst[t]       = *(unsigned short*)&b0;
    dst[t + 256] = *(unsigned short*)&b1;
    float ss = v0 * v0 + v1 * v1;
    #pragma unroll
    for (int off = 32; off > 0; off >>= 1) ss += __shfl_down(ss, off);
    __shared__ float red[4];
    if ((t & 63) == 0) red[t >> 6] = ss;
    __syncthreads();
    if (t == 0) nrm[0] = sqrtf(1.0f + red[0] + red[1] + red[2] + red[3]);
}

// ---------------------------------------------------------------------------
// GEMM: C[m][n] = sum_k A[m][k]*B[n][k]  (both K-major, K=512)
// 128x128 tile, BK=64, 4 waves in 2x2, each wave 64x64 via 4x4 of 16x16x32.
// Epilogue: out = -arccosh(max(x0[m]*p0[n] - acc, 1+eps))
// ---------------------------------------------------------------------------
__global__ __launch_bounds__(256) void gemm_kernel(
    const unsigned short* __restrict__ A,   // [B_ROWS][KP] bf16
    const unsigned short* __restrict__ Bm,  // [C_ROWS][KP] bf16
    const float* __restrict__ xn, const float* __restrict__ pn,
    float* __restrict__ out)
{
    __shared__ unsigned short As[BM * BK];
    __shared__ unsigned short Bs[BN * BK];

    const int tid  = threadIdx.x;
    const int wave = tid >> 6;
    const int lane = tid & 63;
    const int wm   = wave >> 1;        // 0..1
    const int wn   = wave & 1;         // 0..1
    const int lrow = lane & 15;
    const int quad = lane >> 4;        // 0..3

    const int bm0 = blockIdx.x * BM;
    const int bn0 = blockIdx.y * BN;

    // staging: wave covers 32 rows/tile in 4 issues of 8 rows (64 lanes * 16B)
    const int srow = wave * 32 + (lane >> 3);    // + i*8
    const int scol = (lane & 7) * 8;             // element col in [0,64)

    const unsigned short* gA = A  + (size_t)(bm0 + srow) * KP + scol;
    const unsigned short* gB = Bm + (size_t)(bn0 + srow) * KP + scol;

    f32x4 acc[4][4] = {};

    for (int k0 = 0; k0 < KP; k0 += BK) {
        __syncthreads();   // previous iter's LDS reads done
        #pragma unroll
        for (int i = 0; i < 4; ++i) {
            gld16(gA + (size_t)(i * 8) * KP + k0, &As[(wave * 32 + i * 8) * BK]);
            gld16(gB + (size_t)(i * 8) * KP + k0, &Bs[(wave * 32 + i * 8) * BK]);
        }
        __syncthreads();   // compiler emits s_waitcnt vmcnt(0) before barrier

        #pragma unroll
        for (int kk = 0; kk < BK; kk += 32) {
            bf16x8 af[4], bfr[4];
            #pragma unroll
            for (int mi = 0; mi < 4; ++mi)
                af[mi] = *(const bf16x8*)&As[(wm * 64 + mi * 16 + lrow) * BK + kk + quad * 8];
            #pragma unroll
            for (int ni = 0; ni < 4; ++ni)
                bfr[ni] = *(const bf16x8*)&Bs[(wn * 64 + ni * 16 + lrow) * BK + kk + quad * 8];
            #pragma unroll
            for (int mi = 0; mi < 4; ++mi)
                #pragma unroll
                for (int ni = 0; ni < 4; ++ni)
                    acc[mi][ni] = __builtin_amdgcn_mfma_f32_16x16x32_bf16(
                        af[mi], bfr[ni], acc[mi][ni], 0, 0, 0);
        }
    }

    // epilogue: C/D layout col = lane&15, row = quad*4 + reg
    float pv[4];
    #pragma unroll
    for (int ni = 0; ni < 4; ++ni)
        pv[ni] = pn[bn0 + wn * 64 + ni * 16 + lrow];

    #pragma unroll
    for (int mi = 0; mi < 4; ++mi) {
        #pragma unroll
        for (int r = 0; r < 4; ++r) {
            int row = bm0 + wm * 64 + mi * 16 + quad * 4 + r;
            float xv = xn[row];
            size_t base = (size_t)row * C_ROWS + bn0 + wn * 64 + lrow;
            #pragma unroll
            for (int ni = 0; ni < 4; ++ni) {
                float z = fmaf(xv, pv[ni], -acc[mi][ni][r]);
                z = fmaxf(z, 1.0f + 1e-7f);
                // arccosh(z) = log(z + sqrt(z^2-1)); z >= ~20 here, no cancellation
                out[base + ni * 16] = -__logf(z + __fsqrt_rn(z * z - 1.0f));
            }
        }
    }
}

extern "C" void kernel_launch(void* const* d_in, const int* in_sizes, int n_in,
                              void* d_out, int out_size, void* d_ws, size_t ws_size,
                              hipStream_t stream) {
    const float* x   = (const float*)d_in[0];
    const float* pts = (const float*)d_in[1];
    float* out = (float*)d_out;

    char* ws = (char*)d_ws;
    unsigned short* Abf = (unsigned short*)ws;                                 // 16 MB
    unsigned short* Bbf = (unsigned short*)(ws + (size_t)B_ROWS * KP * 2);     // 2 MB
    float* xn = (float*)(ws + (size_t)(B_ROWS + C_ROWS) * KP * 2);             // 64 KB
    float* pn = (float*)((char*)xn + (size_t)B_ROWS * 4);                      // 8 KB
    (void)in_sizes; (void)n_in; (void)out_size; (void)ws_size;

    prep_kernel<<<B_ROWS + C_ROWS, 256, 0, stream>>>(x, pts, Abf, Bbf, xn, pn);

    dim3 grid(B_ROWS / BM, C_ROWS / BN);
    gemm_kernel<<<grid, 256, 0, stream>>>(Abf, Bbf, xn, pn, out);
}

// Round 2
// 199.257 us; speedup vs baseline: 1.0489x; 1.0489x over previous
//
#include <hip/hip_runtime.h>
#include <hip/hip_bf16.h>
#include <stdint.h>

#define B_ROWS 16384   // batch rows (M)
#define C_ROWS 2048    // class rows (N)
#define D_FULL 512     // input feature dim
#define KP     512     // padded K (511 real + 1 zero col)

#define BM 128
#define BN 128
#define BK 64

typedef __attribute__((ext_vector_type(8))) short bf16x8;
typedef __attribute__((ext_vector_type(4))) float f32x4;

typedef __attribute__((address_space(1))) void glb_void;
typedef __attribute__((address_space(3))) void lds_void;

// async global->LDS, 16B per lane; LDS dest = wave-uniform base + lane*16
__device__ __forceinline__ void gld16(const void* g, void* l) {
    __builtin_amdgcn_global_load_lds((glb_void*)(uintptr_t)g,
                                     (lds_void*)(uintptr_t)l, 16, 0, 0);
}

// ---------------------------------------------------------------------------
// Prep: per row, cast cols [1..511] -> bf16 (padded to 512 with trailing 0),
// and compute norm = sqrt(1 + sum(rest^2)) in fp32.
// One 256-thread block per row; rows [0,16384) = x, [16384,18432) = points.
// ---------------------------------------------------------------------------
__global__ __launch_bounds__(256) void prep_kernel(
    const float* __restrict__ x, const float* __restrict__ pts,
    unsigned short* __restrict__ Abf, unsigned short* __restrict__ Bbf,
    float* __restrict__ xn, float* __restrict__ pn)
{
    int row = blockIdx.x;
    const float* src;
    unsigned short* dst;
    float* nrm;
    if (row < B_ROWS) {
        src = x + (size_t)row * D_FULL;
        dst = Abf + (size_t)row * KP;
        nrm = xn + row;
    } else {
        int r = row - B_ROWS;
        src = pts + (size_t)r * D_FULL;
        dst = Bbf + (size_t)r * KP;
        nrm = pn + r;
    }
    int t = threadIdx.x;
    float v0 = src[t + 1];                        // k = t        (t in [0,255])
    float v1 = (t < 255) ? src[t + 257] : 0.0f;   // k = t + 256  (k==511 -> pad 0)
    __hip_bfloat16 b0 = __float2bfloat16(v0);
    __hip_bfloat16 b1 = __float2bfloat16(v1);
    dst[t]       = *(unsigned short*)&b0;
    dst[t + 256] = *(unsigned short*)&b1;
    float ss = v0 * v0 + v1 * v1;
    #pragma unroll
    for (int off = 32; off > 0; off >>= 1) ss += __shfl_down(ss, off);
    __shared__ float red[4];
    if ((t & 63) == 0) red[t >> 6] = ss;
    __syncthreads();
    if (t == 0) nrm[0] = sqrtf(1.0f + red[0] + red[1] + red[2] + red[3]);
}

// ---------------------------------------------------------------------------
// GEMM: C[m][n] = sum_k A[m][k]*B[n][k]  (both K-major, K=512)
// 128x128 tile, BK=64, 4 waves in 2x2, each wave 64x64 via 4x4 of 16x16x32.
// LDS XOR-swizzle: LDS chunk position p of row r holds global 16B-chunk
// (p ^ (r&7)) — staging permutes the SOURCE address (dest must stay
// lane-ordered for global_load_lds); fragment reads XOR the chunk index.
// Kills the 16-way bank conflict of the 128B-stride K-major layout.
// Epilogue: out = -arccosh(max(x0[m]*p0[n] - acc, 1+eps))
// ---------------------------------------------------------------------------
__global__ __launch_bounds__(256) void gemm_kernel(
    const unsigned short* __restrict__ A,   // [B_ROWS][KP] bf16
    const unsigned short* __restrict__ Bm,  // [C_ROWS][KP] bf16
    const float* __restrict__ xn, const float* __restrict__ pn,
    float* __restrict__ out)
{
    __shared__ unsigned short As[BM * BK];
    __shared__ unsigned short Bs[BN * BK];

    const int tid  = threadIdx.x;
    const int wave = tid >> 6;
    const int lane = tid & 63;
    const int wm   = wave >> 1;        // 0..1
    const int wn   = wave & 1;         // 0..1
    const int lrow = lane & 15;
    const int quad = lane >> 4;        // 0..3

    const int bm0 = blockIdx.x * BM;
    const int bn0 = blockIdx.y * BN;

    // staging: wave covers 32 rows/tile in 4 issues of 8 rows (64 lanes * 16B)
    // lane's LDS chunk position = lane&7, row-within-8 = lane>>3.
    // XOR-swizzled global source chunk: (lane&7) ^ (row&7), row&7 == (lane>>3)&7
    const int srow = wave * 32 + (lane >> 3);              // + i*8 (preserves row&7)
    const int scol = (((lane & 7) ^ ((lane >> 3) & 7)) << 3);  // element col in [0,64)

    const unsigned short* gA = A  + (size_t)(bm0 + srow) * KP + scol;
    const unsigned short* gB = Bm + (size_t)(bn0 + srow) * KP + scol;

    f32x4 acc[4][4] = {};

    for (int k0 = 0; k0 < KP; k0 += BK) {
        __syncthreads();   // previous iter's LDS reads done
        #pragma unroll
        for (int i = 0; i < 4; ++i) {
            gld16(gA + (size_t)(i * 8) * KP + k0, &As[(wave * 32 + i * 8) * BK]);
            gld16(gB + (size_t)(i * 8) * KP + k0, &Bs[(wave * 32 + i * 8) * BK]);
        }
        __syncthreads();   // compiler emits s_waitcnt vmcnt(0) before barrier

        #pragma unroll
        for (int kk = 0; kk < BK; kk += 32) {
            const int ch0 = kk >> 3;             // chunk base: 0 or 4
            bf16x8 af[4], bfr[4];
            #pragma unroll
            for (int mi = 0; mi < 4; ++mi) {
                int r = wm * 64 + mi * 16 + lrow;
                af[mi] = *(const bf16x8*)&As[r * BK + (((ch0 + quad) ^ (lrow & 7)) << 3)];
            }
            #pragma unroll
            for (int ni = 0; ni < 4; ++ni) {
                int r = wn * 64 + ni * 16 + lrow;
                bfr[ni] = *(const bf16x8*)&Bs[r * BK + (((ch0 + quad) ^ (lrow & 7)) << 3)];
            }
            #pragma unroll
            for (int mi = 0; mi < 4; ++mi)
                #pragma unroll
                for (int ni = 0; ni < 4; ++ni)
                    acc[mi][ni] = __builtin_amdgcn_mfma_f32_16x16x32_bf16(
                        af[mi], bfr[ni], acc[mi][ni], 0, 0, 0);
        }
    }

    // epilogue: C/D layout col = lane&15, row = quad*4 + reg
    float pv[4];
    #pragma unroll
    for (int ni = 0; ni < 4; ++ni)
        pv[ni] = pn[bn0 + wn * 64 + ni * 16 + lrow];

    #pragma unroll
    for (int mi = 0; mi < 4; ++mi) {
        #pragma unroll
        for (int r = 0; r < 4; ++r) {
            int row = bm0 + wm * 64 + mi * 16 + quad * 4 + r;
            float xv = xn[row];
            size_t base = (size_t)row * C_ROWS + bn0 + wn * 64 + lrow;
            #pragma unroll
            for (int ni = 0; ni < 4; ++ni) {
                float z = fmaf(xv, pv[ni], -acc[mi][ni][r]);
                z = fmaxf(z, 1.0f + 1e-7f);
                // arccosh(z) = log(z + sqrt(z^2-1)); z >= ~20 here, no cancellation
                out[base + ni * 16] = -__logf(z + __fsqrt_rn(z * z - 1.0f));
            }
        }
    }
}

extern "C" void kernel_launch(void* const* d_in, const int* in_sizes, int n_in,
                              void* d_out, int out_size, void* d_ws, size_t ws_size,
                              hipStream_t stream) {
    const float* x   = (const float*)d_in[0];
    const float* pts = (const float*)d_in[1];
    float* out = (float*)d_out;

    char* ws = (char*)d_ws;
    unsigned short* Abf = (unsigned short*)ws;                                 // 16 MB
    unsigned short* Bbf = (unsigned short*)(ws + (size_t)B_ROWS * KP * 2);     // 2 MB
    float* xn = (float*)(ws + (size_t)(B_ROWS + C_ROWS) * KP * 2);             // 64 KB
    float* pn = (float*)((char*)xn + (size_t)B_ROWS * 4);                      // 8 KB
    (void)in_sizes; (void)n_in; (void)out_size; (void)ws_size;

    prep_kernel<<<B_ROWS + C_ROWS, 256, 0, stream>>>(x, pts, Abf, Bbf, xn, pn);

    dim3 grid(B_ROWS / BM, C_ROWS / BN);
    gemm_kernel<<<grid, 256, 0, stream>>>(Abf, Bbf, xn, pn, out);
}